// Round 16
// baseline (2478.393 us; speedup 1.0000x reference)
//
#include <hip/hip_runtime.h>
#include <math.h>

// dims
#define KP   32      // particles
#define BB   32      // batch
#define TT   64      // seq len
#define HH   256     // hidden
#define KB   1024    // KP*BB

// ---------------- Threefry-2x32 (JAX partitionable semantics) ----------------
__host__ __device__ __forceinline__ unsigned rotl32(unsigned v, int s) {
  return (v << s) | (v >> (32 - s));
}
__host__ __device__ __forceinline__ void tf2x32(unsigned k0, unsigned k1,
                                                unsigned c0, unsigned c1,
                                                unsigned& o0, unsigned& o1) {
  unsigned ks2 = k0 ^ k1 ^ 0x1BD11BDAu;
  unsigned x0 = c0 + k0, x1 = c1 + k1;
#define TF_R4(a,b,c,d)                                           \
  x0 += x1; x1 = rotl32(x1, a); x1 ^= x0;                        \
  x0 += x1; x1 = rotl32(x1, b); x1 ^= x0;                        \
  x0 += x1; x1 = rotl32(x1, c); x1 ^= x0;                        \
  x0 += x1; x1 = rotl32(x1, d); x1 ^= x0;
  TF_R4(13,15,26,6)  x0 += k1;  x1 += ks2 + 1u;
  TF_R4(17,29,16,24) x0 += ks2; x1 += k0 + 2u;
  TF_R4(13,15,26,6)  x0 += k0;  x1 += k1 + 3u;
  TF_R4(17,29,16,24) x0 += k1;  x1 += ks2 + 4u;
  TF_R4(13,15,26,6)  x0 += ks2; x1 += k0 + 5u;
#undef TF_R4
  o0 = x0; o1 = x1;
}
__device__ __forceinline__ unsigned tfx(unsigned k0, unsigned k1, unsigned ctr) {
  unsigned a, b;
  tf2x32(k0, k1, 0u, ctr, a, b);
  return a ^ b;
}

// ---------------- math helpers matching XLA f32 lowerings ----------------
__device__ __forceinline__ float sigf(float x) { return 1.0f / (1.0f + expf(-x)); }

__device__ __forceinline__ float erfinv_f(float x) {  // XLA ErfInv f32 polynomial
  float w = -log1pf(-x * x);
  float p;
  if (w < 5.0f) {
    w -= 2.5f;
    p = 2.81022636e-08f;
    p = fmaf(p, w, 3.43273939e-07f);
    p = fmaf(p, w, -3.5233877e-06f);
    p = fmaf(p, w, -4.39150654e-06f);
    p = fmaf(p, w, 0.00021858087f);
    p = fmaf(p, w, -0.00125372503f);
    p = fmaf(p, w, -0.00417768164f);
    p = fmaf(p, w, 0.246640727f);
    p = fmaf(p, w, 1.50140941f);
  } else {
    w = sqrtf(w) - 3.0f;
    p = -0.000200214257f;
    p = fmaf(p, w, 0.000100950558f);
    p = fmaf(p, w, 0.00134934322f);
    p = fmaf(p, w, -0.00367342844f);
    p = fmaf(p, w, 0.00573950773f);
    p = fmaf(p, w, -0.0076224613f);
    p = fmaf(p, w, 0.00943887047f);
    p = fmaf(p, w, 1.00167406f);
    p = fmaf(p, w, 2.83297682f);
  }
  return p * x;
}

__device__ __forceinline__ float normal_from_bits(unsigned bits) {
  float u01 = __uint_as_float(0x3f800000u | (bits >> 9)) - 1.0f;
  const float lo = -0.99999994f;
  float u = fmaxf(fmaf(u01, 2.0f, lo), lo);
  return 1.41421354f * erfinv_f(u);
}

// ---------------- weight transpose: W[j=g*256+h][k] -> Wt5[k4][h][g] --------
__global__ __launch_bounds__(256) void transpose_w_kernel(
    const float* __restrict__ W, float4* __restrict__ Wt5) {
  int idx = blockIdx.x * 256 + threadIdx.x;   // 64*256*5 = 81920
  int k4 = idx / 1280;
  int r  = idx - k4 * 1280;
  int h  = r / 5, g = r - h * 5;
  Wt5[idx] = *(const float4*)&W[(size_t)(g * 256 + h) * 256 + k4 * 4];
}

// ---------------- pre-compute kernels ----------------
__global__ __launch_bounds__(256) void emb_kernel(
    const float* __restrict__ obs, const float* __restrict__ win,
    const float* __restrict__ Wobs, const float* __restrict__ bobs,
    const float* __restrict__ Wact, const float* __restrict__ bact,
    float* __restrict__ embT) {
  int r = blockIdx.x;            // r = t*32 + b
  int t = r >> 5, b = r & 31;
  __shared__ float xs[64];
  __shared__ float ws[50];
  int tid = threadIdx.x;
  if (tid < 64) xs[tid] = obs[(b * 64 + t) * 64 + tid];
  else if (tid < 114) ws[tid - 64] = win[(b * 64 + t) * 50 + (tid - 64)];
  __syncthreads();
  int e = tid;
  float acc = 0.0f;
  if (e < 128) {
    const float* wr = Wobs + e * 64;
    for (int o = 0; o < 64; ++o) acc = fmaf(xs[o], wr[o], acc);
    acc += bobs[e];
  } else {
    int e2 = e - 128;
    const float* wr = Wact + e2 * 50;
    for (int o = 0; o < 50; ++o) acc = fmaf(ws[o], wr[o], acc);
    acc += bact[e2];
  }
  embT[r * 256 + e] = fmaxf(acc, 0.0f);
}

__global__ __launch_bounds__(256) void xdot_kernel(
    const float* __restrict__ embT, const float* __restrict__ Wf,
    const float* __restrict__ bf, float* __restrict__ xdot) {
  int wave = threadIdx.x >> 6, lane = threadIdx.x & 63;
  int r = blockIdx.x * 4 + wave;  // 2048 rows
  const float4* row = (const float4*)(embT + (size_t)r * 256);
  const float4* wv  = (const float4*)(Wf + 256);
  float4 a = row[lane];
  float4 w = wv[lane];
  float s = a.x * w.x + a.y * w.y + a.z * w.z + a.w * w.w;
  for (int m = 1; m < 64; m <<= 1) s += __shfl_xor(s, m);
  if (lane == 0) xdot[r] = s + bf[0];
}

// xw[t*B+b][j] = emb @ W_ih^T + b_ih + b_hh  (256 blk, R=8)
__global__ __launch_bounds__(256, 2) void xw_kernel(
    const float* __restrict__ embT, const float4* __restrict__ Wt5ih,
    const float* __restrict__ bih, const float* __restrict__ bhh,
    float* __restrict__ xw) {
  int cg = blockIdx.x & 7;    // 8 col groups of 32 h-cols
  int rt = blockIdx.x >> 3;   // 32 row tiles of 64 rows
  __shared__ float h_s[64 * 256];
  int tid = threadIdx.x;
  {
    const float4* src = (const float4*)(embT + (size_t)rt * 64 * 256);
    float4* dst = (float4*)h_s;
    for (int i = tid; i < 64 * 64; i += 256) dst[i] = src[i];
  }
  __syncthreads();
  int rg = tid >> 5, hcol = tid & 31;       // rg in [0,8): 8 rows each
  int jh = cg * 32 + hcol;
  const float4* wp = Wt5ih + (size_t)jh * 5;
  const float* hb = h_s + rg * 8 * 256;
  float acc[8][5] = {};
  #pragma unroll 2
  for (int k4 = 0; k4 < 64; ++k4) {
    float4 wv[5], hv[8];
    #pragma unroll
    for (int g = 0; g < 5; ++g) wv[g] = wp[(size_t)k4 * 1280 + g];
    #pragma unroll
    for (int i = 0; i < 8; ++i)
      hv[i] = *(const float4*)&hb[i * 256 + k4 * 4];
    #pragma unroll
    for (int i = 0; i < 8; ++i)
      #pragma unroll
      for (int g = 0; g < 5; ++g) {
        acc[i][g] = fmaf(hv[i].x, wv[g].x, acc[i][g]);
        acc[i][g] = fmaf(hv[i].y, wv[g].y, acc[i][g]);
        acc[i][g] = fmaf(hv[i].z, wv[g].z, acc[i][g]);
        acc[i][g] = fmaf(hv[i].w, wv[g].w, acc[i][g]);
      }
  }
  for (int i = 0; i < 8; ++i) {
    int r = rt * 64 + rg * 8 + i;
    for (int g = 0; g < 5; ++g) {
      int j = g * 256 + jh;
      xw[(size_t)r * 1280 + j] = acc[i][g] + bih[j] + bhh[j];
    }
  }
}

// ---------------- per-step kernel (R10 geometry + entry prefetch) ----------
// grid = 256 blocks (rt 32 x cg 8), 256 threads, R=4 rows/thread.
// Entry touch-prefetch warms the (per-dispatch-invalidated) L2 with this
// block's weight slice + the step's xw slice, overlapping phase C.
__global__ __launch_bounds__(256, 2) void step_kernel(
    int t, unsigned ke0, unsigned ke1, unsigned kr0, unsigned kr1,
    const float* __restrict__ h_prev, const float* __restrict__ c_prev,
    float* __restrict__ h_next, float* __restrict__ c_next,
    const float* __restrict__ parts_prev, float* __restrict__ parts_cur,
    const float* __restrict__ labparts_prev, float* __restrict__ labparts_cur,
    const float* __restrict__ ps_prev, float* __restrict__ ps_out,
    float* __restrict__ lab_out, float* __restrict__ pf_out,
    const float* __restrict__ xdot, const float* __restrict__ xw,
    const float4* __restrict__ Wt5hh, const float* __restrict__ Wf,
    const float* __restrict__ Wlab, const float* __restrict__ blab) {
  const int tid = threadIdx.x;
  const int cg = blockIdx.x & 7;
  const int rt = blockIdx.x >> 3;

  __shared__ float sarr[1024];
  __shared__ float mtab[32], ltab[32];
  __shared__ int   flat_s[32];
  __shared__ float h_s[32 * 256];

  // ---- entry touch-prefetch: issue independent line loads NOW; the sink
  //      (empty asm) is at kernel end so no wait blocks real work. ----
  float pf = 0.0f;
  {
    const float* wflat = (const float*)Wt5hh;
    #pragma unroll
    for (int l5 = 0; l5 < 5; ++l5) {               // 1280 lines of W slice
      int l = tid + l5 * 256;
      int k4 = l / 20, li = l - k4 * 20;
      pf += wflat[(size_t)(k4 * 1280 + cg * 160 + li * 8) * 4];
    }
    const float* xbase = xw + (size_t)(t * 32) * 1280;  // 160 KB xw slice
    #pragma unroll
    for (int l5 = 0; l5 < 5; ++l5) {
      int l = tid + l5 * 256;
      pf += xbase[(size_t)l * 32];
    }
  }

  if (t == 0) {
    if (tid < 32) flat_s[tid] = rt * 32 + tid;   // identity gather
  } else {
    // ---- phase C: resample step t-1 ----
    for (int idx = tid; idx < 1024; idx += 256) {
      float lp = 0.0f;
      #pragma unroll
      for (int c2 = 0; c2 < 8; ++c2) lp += parts_prev[c2 * 1024 + idx];
      lp += xdot[(t - 1) * 32 + (idx & 31)];
      float pp = ps_prev ? ps_prev[idx] : -3.4657359f;  // log(1/32)
      sarr[idx] = lp + pp;
    }
    __syncthreads();
    if (tid < 32) {  // per-b softmax stats over particles
      const int b = tid;
      float m = -INFINITY;
      for (int k = 0; k < 32; ++k) m = fmaxf(m, sarr[k * 32 + b]);
      float s = 0.0f;
      for (int k = 0; k < 32; ++k) s += expf(sarr[k * 32 + b] - m);
      mtab[b] = m; ltab[b] = logf(s);
    }
    __syncthreads();
    {
      // Gumbel argmax for (k=rt, b=q) rows: 8 lanes per row, 4 j each
      const int q = tid >> 3, s8 = tid & 7;
      const float m = mtab[q], l = ltab[q];
      float best = -INFINITY; int bestj = 0;
      for (int jj = 0; jj < 4; ++jj) {
        int j = s8 * 4 + jj;
        unsigned bits = tfx(kr0, kr1, (unsigned)(rt * 1024 + q * 32 + j));
        float u01 = __uint_as_float(0x3f800000u | (bits >> 9)) - 1.0f;
        float u = fmaxf(u01, 1.17549435e-38f);
        float g = -logf(-logf(u));
        float p1 = sarr[j * 32 + q] - m - l;
        float z = g + logf(fmaf(0.5f, expf(p1), 0.015625f));
        if (z > best) { best = z; bestj = j; }
      }
      #pragma unroll
      for (int mm = 1; mm < 8; mm <<= 1) {
        float ob = __shfl_xor(best, mm);
        int   oj = __shfl_xor(bestj, mm);
        if (ob > best || (ob == best && oj < bestj)) { best = ob; bestj = oj; }
      }
      if (s8 == 0) {
        int fl = bestj * 32 + q;
        flat_s[q] = fl;
        if (cg == 0) {   // unnormalized importance-corrected log-weight
          float p1f = sarr[fl] - m - l;
          float e = expf(p1f);
          ps_out[rt * 32 + q] = logf(e / fmaf(0.5f, e, 0.015625f));
        }
      }
    }
    if (cg == 0) {  // gathered label-head dot for outputs of step t-1
      __syncthreads();
      if (tid < 32) {
        int fl = flat_s[tid];
        float lab = 0.0f;
        #pragma unroll
        for (int c2 = 0; c2 < 8; ++c2) lab += labparts_prev[c2 * 1024 + fl];
        lab_out[rt * 32 + tid] = lab;
        float v = lab + blab[0];
        pf_out[rt * 32 + tid] = 1.0f / (1.0f + expf(-v));
      }
    }
  }
  __syncthreads();

  // ---- phase A: stage gathered h rows into LDS ----
  {
    float4* dst = (float4*)h_s;
    for (int i = tid; i < 32 * 64; i += 256) {
      int rr = i >> 6, kc = i & 63;
      dst[i] = *(const float4*)(h_prev + (size_t)flat_s[rr] * 256 + kc * 4);
    }
  }
  __syncthreads();

  const int rg = tid >> 5, hcol = tid & 31;  // rg in [0,8): 4 rows each
  const int jh = cg * 32 + hcol;             // hidden index 0..255
  const float4* wp = Wt5hh + (size_t)jh * 5;
  const float* hb = h_s + rg * 4 * 256;
  float acc[4][5] = {};
  #pragma unroll 4
  for (int k4 = 0; k4 < 64; ++k4) {
    float4 wv[5], hv[4];
    #pragma unroll
    for (int g = 0; g < 5; ++g) wv[g] = wp[(size_t)k4 * 1280 + g];
    #pragma unroll
    for (int i = 0; i < 4; ++i)
      hv[i] = *(const float4*)&hb[i * 256 + k4 * 4];
    #pragma unroll
    for (int i = 0; i < 4; ++i)
      #pragma unroll
      for (int g = 0; g < 5; ++g) {
        acc[i][g] = fmaf(hv[i].x, wv[g].x, acc[i][g]);
        acc[i][g] = fmaf(hv[i].y, wv[g].y, acc[i][g]);
        acc[i][g] = fmaf(hv[i].z, wv[g].z, acc[i][g]);
        acc[i][g] = fmaf(hv[i].w, wv[g].w, acc[i][g]);
      }
  }

  const float wfj = Wf[jh];
  const float wlj = Wlab[jh];
  #pragma unroll
  for (int i = 0; i < 4; ++i) {
    const int rl = rg * 4 + i;             // local row == b
    const int kb = rt * 32 + rl;
    const float* xr = xw + (size_t)(t * 32 + rl) * 1280;
    float gi = acc[i][0] + xr[jh];
    float gf = acc[i][1] + xr[256 + jh];
    float gg = acc[i][2] + xr[512 + jh];
    float go = acc[i][3] + xr[768 + jh];
    float gv = acc[i][4] + xr[1024 + jh];
    float cp = c_prev[(size_t)flat_s[rl] * 256 + jh];
    float c1 = sigf(gf) * cp + sigf(gi) * tanhf(gg);
    unsigned bits = tfx(ke0, ke1, (unsigned)(kb * 256 + jh));
    float z = normal_from_bits(bits);
    float sp = fmaxf(gv, 0.0f) + log1pf(expf(-fabsf(gv)));  // softplus
    c1 = c1 + z * sp;
    float h1 = sigf(go) * tanhf(c1);
    h_next[(size_t)kb * 256 + jh] = h1;
    c_next[(size_t)kb * 256 + jh] = c1;
    float ph = h1 * wfj, pb = h1 * wlj;
    #pragma unroll
    for (int mm = 1; mm < 32; mm <<= 1) {
      ph += __shfl_xor(ph, mm);
      pb += __shfl_xor(pb, mm);
    }
    if (hcol == 0) {
      parts_cur[cg * 1024 + kb] = ph;
      labparts_cur[cg * 1024 + kb] = pb;
    }
  }

  // sink for the prefetch accumulator: keeps the touch loads alive with no
  // architectural side effect; waitcnt lands here, after all real work.
  __asm__ volatile("" : : "v"(pf));
}

// ---------------- tail resample (t=63): one block per particle -------------
__global__ __launch_bounds__(256, 2) void tail_resample_kernel(
    unsigned kr0, unsigned kr1,
    const float* __restrict__ parts_prev,
    const float* __restrict__ labparts_prev,
    const float* __restrict__ ps_prev, float* __restrict__ ps_out,
    float* __restrict__ lab_out, float* __restrict__ pf_out,
    const float* __restrict__ xdot, const float* __restrict__ blab) {
  const int tid = threadIdx.x;
  const int rt = blockIdx.x;      // particle

  __shared__ float sarr[1024];
  __shared__ float mtab[32], ltab[32];
  __shared__ int   flat_s[32];

  for (int idx = tid; idx < 1024; idx += 256) {
    float lp = 0.0f;
    #pragma unroll
    for (int c2 = 0; c2 < 8; ++c2) lp += parts_prev[c2 * 1024 + idx];
    lp += xdot[63 * 32 + (idx & 31)];
    float pp = ps_prev[idx];
    sarr[idx] = lp + pp;
  }
  __syncthreads();
  if (tid < 32) {
    const int b = tid;
    float m = -INFINITY;
    for (int k = 0; k < 32; ++k) m = fmaxf(m, sarr[k * 32 + b]);
    float s = 0.0f;
    for (int k = 0; k < 32; ++k) s += expf(sarr[k * 32 + b] - m);
    mtab[b] = m; ltab[b] = logf(s);
  }
  __syncthreads();
  {
    const int q = tid >> 3, s8 = tid & 7;
    const float m = mtab[q], l = ltab[q];
    float best = -INFINITY; int bestj = 0;
    for (int jj = 0; jj < 4; ++jj) {
      int j = s8 * 4 + jj;
      unsigned bits = tfx(kr0, kr1, (unsigned)(rt * 1024 + q * 32 + j));
      float u01 = __uint_as_float(0x3f800000u | (bits >> 9)) - 1.0f;
      float u = fmaxf(u01, 1.17549435e-38f);
      float g = -logf(-logf(u));
      float p1 = sarr[j * 32 + q] - m - l;
      float z = g + logf(fmaf(0.5f, expf(p1), 0.015625f));
      if (z > best) { best = z; bestj = j; }
    }
    #pragma unroll
    for (int mm = 1; mm < 8; mm <<= 1) {
      float ob = __shfl_xor(best, mm);
      int   oj = __shfl_xor(bestj, mm);
      if (ob > best || (ob == best && oj < bestj)) { best = ob; bestj = oj; }
    }
    if (s8 == 0) {
      int fl = bestj * 32 + q;
      flat_s[q] = fl;
      float p1f = sarr[fl] - m - l;
      float e = expf(p1f);
      ps_out[rt * 32 + q] = logf(e / fmaf(0.5f, e, 0.015625f));
    }
  }
  __syncthreads();
  if (tid < 32) {
    int fl = flat_s[tid];
    float lab = 0.0f;
    #pragma unroll
    for (int c2 = 0; c2 < 8; ++c2) lab += labparts_prev[c2 * 1024 + fl];
    lab_out[rt * 32 + tid] = lab;
    float v = lab + blab[0];
    pf_out[rt * 32 + tid] = 1.0f / (1.0f + expf(-v));
  }
}

// ---------------- final: weighted particle mean -> y_out ----------------
__global__ __launch_bounds__(256) void final_kernel(
    const float* __restrict__ ps_store, const float* __restrict__ lab_full,
    const float* __restrict__ blab, float* __restrict__ yout) {
  int idx = blockIdx.x * 256 + threadIdx.x;  // T*B = 2048
  if (idx >= 2048) return;
  int t = idx >> 5, b = idx & 31;
  const float* pl = ps_store + (size_t)t * 1024 + b;
  const float* lb = lab_full + (size_t)t * 1024 + b;
  float m = -INFINITY;
  for (int k = 0; k < 32; ++k) m = fmaxf(m, pl[k * 32]);
  float num = 0.0f, den = 0.0f;
  for (int k = 0; k < 32; ++k) {
    float w = expf(pl[k * 32] - m);
    num += w * lb[k * 32];
    den += w;
  }
  float y = num / den;
  yout[idx] = 1.0f / (1.0f + expf(-(y + blab[0])));
}

// ---------------- host ----------------
extern "C" void kernel_launch(void* const* d_in, const int* in_sizes, int n_in,
                              void* d_out, int out_size, void* d_ws,
                              size_t ws_size, hipStream_t stream) {
  const float* obs  = (const float*)d_in[0];
  const float* win  = (const float*)d_in[1];
  const float* Wobs = (const float*)d_in[2];
  const float* bobs = (const float*)d_in[3];
  const float* Wact = (const float*)d_in[4];
  const float* bact = (const float*)d_in[5];
  const float* Wih  = (const float*)d_in[6];
  const float* bih  = (const float*)d_in[7];
  const float* Whh  = (const float*)d_in[8];
  const float* bhh  = (const float*)d_in[9];
  const float* Wf   = (const float*)d_in[10];
  const float* bf   = (const float*)d_in[11];
  const float* Wlab = (const float*)d_in[12];
  const float* blab = (const float*)d_in[13];
  const float* h0   = (const float*)d_in[14];
  const float* c0   = (const float*)d_in[15];
  float* out = (float*)d_out;

  char* ws = (char*)d_ws;
  float* embT = (float*)ws;                 ws += (size_t)2048 * 256 * 4;
  float* xw   = (float*)ws;                 ws += (size_t)2048 * 1280 * 4;
  float* xd   = (float*)ws;                 ws += (size_t)2048 * 4;
  float* hbuf[2]; float* cbuf[2];
  hbuf[0] = (float*)ws;                     ws += (size_t)1024 * 256 * 4;
  hbuf[1] = (float*)ws;                     ws += (size_t)1024 * 256 * 4;
  cbuf[0] = (float*)ws;                     ws += (size_t)1024 * 256 * 4;
  cbuf[1] = (float*)ws;                     ws += (size_t)1024 * 256 * 4;
  float* parts    = (float*)ws;             ws += (size_t)2 * 8 * 1024 * 4;
  float* labparts = (float*)ws;             ws += (size_t)2 * 8 * 1024 * 4;
  float* psst     = (float*)ws;             ws += (size_t)64 * 1024 * 4;
  float* labf     = (float*)ws;             ws += (size_t)64 * 1024 * 4;

  // Aliased transposed-weight buffers (no net workspace growth):
  // Wt5ih: starts at hbuf[1], 1.31 MB (spills 0.26 MB into cbuf[0]) — last
  //        read by xw_kernel, which completes before step 0 writes hbuf/cbuf
  //        (stream-serial; step 0 reads c from the pristine c0 input).
  // Wt5hh: embT region (2 MB) — embT dead after xw_kernel/xdot_kernel.
  float4* Wt5ih = (float4*)hbuf[1];
  float4* Wt5hh = (float4*)embT;

  transpose_w_kernel<<<320, 256, 0, stream>>>(Wih, Wt5ih);
  emb_kernel<<<2048, 256, 0, stream>>>(obs, win, Wobs, bobs, Wact, bact, embT);
  xw_kernel<<<256, 256, 0, stream>>>(embT, Wt5ih, bih, bhh, xw);
  xdot_kernel<<<512, 256, 0, stream>>>(embT, Wf, bf, xd);
  transpose_w_kernel<<<320, 256, 0, stream>>>(Whh, Wt5hh);

  for (int t = 0; t < 64; ++t) {
    unsigned a0, a1, ke0 = 0, ke1 = 0, kr0 = 0, kr1 = 0;
    tf2x32(0u, 42u, 0u, (unsigned)t, a0, a1);
    tf2x32(a0, a1, 0u, 0u, ke0, ke1);
    if (t >= 1) {  // k_res of step t-1 (resample performed this launch)
      tf2x32(0u, 42u, 0u, (unsigned)(t - 1), a0, a1);
      tf2x32(a0, a1, 0u, 1u, kr0, kr1);
    }
    const float* hp = (t == 0) ? h0 : hbuf[(t - 1) & 1];
    const float* cp = (t == 0) ? c0 : cbuf[(t - 1) & 1];
    float* hn = hbuf[t & 1];
    float* cn = cbuf[t & 1];
    const float* pprev = (t >= 2) ? psst + (size_t)(t - 2) * 1024 : nullptr;
    int tm1 = (t >= 1) ? (t - 1) : 0;
    step_kernel<<<256, 256, 0, stream>>>(
        t, ke0, ke1, kr0, kr1, hp, cp, hn, cn,
        parts + (size_t)((t + 1) & 1) * 8192, parts + (size_t)(t & 1) * 8192,
        labparts + (size_t)((t + 1) & 1) * 8192,
        labparts + (size_t)(t & 1) * 8192,
        pprev, psst + (size_t)tm1 * 1024, labf + (size_t)tm1 * 1024,
        out + 2048 + (size_t)tm1 * 1024,
        xd, xw, Wt5hh, Wf, Wlab, blab);
  }

  {  // resample for t=63 (32 blocks)
    unsigned a0, a1, kr0, kr1;
    tf2x32(0u, 42u, 0u, 63u, a0, a1);
    tf2x32(a0, a1, 0u, 1u, kr0, kr1);
    tail_resample_kernel<<<32, 256, 0, stream>>>(
        kr0, kr1, parts + 8192, labparts + 8192,
        psst + (size_t)62 * 1024, psst + (size_t)63 * 1024,
        labf + (size_t)63 * 1024, out + 2048 + (size_t)63 * 1024, xd, blab);
  }

  final_kernel<<<8, 256, 0, stream>>>(psst, labf, blab, out);
  (void)in_sizes; (void)n_in; (void)out_size; (void)ws_size;
}

// Round 17
// 2090.219 us; speedup vs baseline: 1.1857x; 1.1857x over previous
//
#include <hip/hip_runtime.h>
#include <math.h>

// dims
#define KP   32      // particles
#define BB   32      // batch
#define TT   64      // seq len
#define HH   256     // hidden
#define KB   1024    // KP*BB

// ---------------- Threefry-2x32 (JAX partitionable semantics) ----------------
__host__ __device__ __forceinline__ unsigned rotl32(unsigned v, int s) {
  return (v << s) | (v >> (32 - s));
}
__host__ __device__ __forceinline__ void tf2x32(unsigned k0, unsigned k1,
                                                unsigned c0, unsigned c1,
                                                unsigned& o0, unsigned& o1) {
  unsigned ks2 = k0 ^ k1 ^ 0x1BD11BDAu;
  unsigned x0 = c0 + k0, x1 = c1 + k1;
#define TF_R4(a,b,c,d)                                           \
  x0 += x1; x1 = rotl32(x1, a); x1 ^= x0;                        \
  x0 += x1; x1 = rotl32(x1, b); x1 ^= x0;                        \
  x0 += x1; x1 = rotl32(x1, c); x1 ^= x0;                        \
  x0 += x1; x1 = rotl32(x1, d); x1 ^= x0;
  TF_R4(13,15,26,6)  x0 += k1;  x1 += ks2 + 1u;
  TF_R4(17,29,16,24) x0 += ks2; x1 += k0 + 2u;
  TF_R4(13,15,26,6)  x0 += k0;  x1 += k1 + 3u;
  TF_R4(17,29,16,24) x0 += k1;  x1 += ks2 + 4u;
  TF_R4(13,15,26,6)  x0 += ks2; x1 += k0 + 5u;
#undef TF_R4
  o0 = x0; o1 = x1;
}
__device__ __forceinline__ unsigned tfx(unsigned k0, unsigned k1, unsigned ctr) {
  unsigned a, b;
  tf2x32(k0, k1, 0u, ctr, a, b);
  return a ^ b;
}

// ---------------- math helpers matching XLA f32 lowerings ----------------
__device__ __forceinline__ float sigf(float x) { return 1.0f / (1.0f + expf(-x)); }

__device__ __forceinline__ float erfinv_f(float x) {  // XLA ErfInv f32 polynomial
  float w = -log1pf(-x * x);
  float p;
  if (w < 5.0f) {
    w -= 2.5f;
    p = 2.81022636e-08f;
    p = fmaf(p, w, 3.43273939e-07f);
    p = fmaf(p, w, -3.5233877e-06f);
    p = fmaf(p, w, -4.39150654e-06f);
    p = fmaf(p, w, 0.00021858087f);
    p = fmaf(p, w, -0.00125372503f);
    p = fmaf(p, w, -0.00417768164f);
    p = fmaf(p, w, 0.246640727f);
    p = fmaf(p, w, 1.50140941f);
  } else {
    w = sqrtf(w) - 3.0f;
    p = -0.000200214257f;
    p = fmaf(p, w, 0.000100950558f);
    p = fmaf(p, w, 0.00134934322f);
    p = fmaf(p, w, -0.00367342844f);
    p = fmaf(p, w, 0.00573950773f);
    p = fmaf(p, w, -0.0076224613f);
    p = fmaf(p, w, 0.00943887047f);
    p = fmaf(p, w, 1.00167406f);
    p = fmaf(p, w, 2.83297682f);
  }
  return p * x;
}

__device__ __forceinline__ float normal_from_bits(unsigned bits) {
  float u01 = __uint_as_float(0x3f800000u | (bits >> 9)) - 1.0f;
  const float lo = -0.99999994f;
  float u = fmaxf(fmaf(u01, 2.0f, lo), lo);
  return 1.41421354f * erfinv_f(u);
}

// ---------------- weight transpose: W[j=g*256+h][k] -> Wt5[k4][h][g] --------
__global__ __launch_bounds__(256) void transpose_w_kernel(
    const float* __restrict__ W, float4* __restrict__ Wt5) {
  int idx = blockIdx.x * 256 + threadIdx.x;   // 64*256*5 = 81920
  int k4 = idx / 1280;
  int r  = idx - k4 * 1280;
  int h  = r / 5, g = r - h * 5;
  Wt5[idx] = *(const float4*)&W[(size_t)(g * 256 + h) * 256 + k4 * 4];
}

// ---------------- pre-compute kernels ----------------
__global__ __launch_bounds__(256) void emb_kernel(
    const float* __restrict__ obs, const float* __restrict__ win,
    const float* __restrict__ Wobs, const float* __restrict__ bobs,
    const float* __restrict__ Wact, const float* __restrict__ bact,
    float* __restrict__ embT) {
  int r = blockIdx.x;            // r = t*32 + b
  int t = r >> 5, b = r & 31;
  __shared__ float xs[64];
  __shared__ float ws[50];
  int tid = threadIdx.x;
  if (tid < 64) xs[tid] = obs[(b * 64 + t) * 64 + tid];
  else if (tid < 114) ws[tid - 64] = win[(b * 64 + t) * 50 + (tid - 64)];
  __syncthreads();
  int e = tid;
  float acc = 0.0f;
  if (e < 128) {
    const float* wr = Wobs + e * 64;
    for (int o = 0; o < 64; ++o) acc = fmaf(xs[o], wr[o], acc);
    acc += bobs[e];
  } else {
    int e2 = e - 128;
    const float* wr = Wact + e2 * 50;
    for (int o = 0; o < 50; ++o) acc = fmaf(ws[o], wr[o], acc);
    acc += bact[e2];
  }
  embT[r * 256 + e] = fmaxf(acc, 0.0f);
}

__global__ __launch_bounds__(256) void xdot_kernel(
    const float* __restrict__ embT, const float* __restrict__ Wf,
    const float* __restrict__ bf, float* __restrict__ xdot) {
  int wave = threadIdx.x >> 6, lane = threadIdx.x & 63;
  int r = blockIdx.x * 4 + wave;  // 2048 rows
  const float4* row = (const float4*)(embT + (size_t)r * 256);
  const float4* wv  = (const float4*)(Wf + 256);
  float4 a = row[lane];
  float4 w = wv[lane];
  float s = a.x * w.x + a.y * w.y + a.z * w.z + a.w * w.w;
  for (int m = 1; m < 64; m <<= 1) s += __shfl_xor(s, m);
  if (lane == 0) xdot[r] = s + bf[0];
}

// xw[t*B+b][j] = emb @ W_ih^T + b_ih + b_hh  (256 blk, R=8)
__global__ __launch_bounds__(256, 2) void xw_kernel(
    const float* __restrict__ embT, const float4* __restrict__ Wt5ih,
    const float* __restrict__ bih, const float* __restrict__ bhh,
    float* __restrict__ xw) {
  int cg = blockIdx.x & 7;    // 8 col groups of 32 h-cols
  int rt = blockIdx.x >> 3;   // 32 row tiles of 64 rows
  __shared__ float h_s[64 * 256];
  int tid = threadIdx.x;
  {
    const float4* src = (const float4*)(embT + (size_t)rt * 64 * 256);
    float4* dst = (float4*)h_s;
    for (int i = tid; i < 64 * 64; i += 256) dst[i] = src[i];
  }
  __syncthreads();
  int rg = tid >> 5, hcol = tid & 31;       // rg in [0,8): 8 rows each
  int jh = cg * 32 + hcol;
  const float4* wp = Wt5ih + (size_t)jh * 5;
  const float* hb = h_s + rg * 8 * 256;
  float acc[8][5] = {};
  #pragma unroll 2
  for (int k4 = 0; k4 < 64; ++k4) {
    float4 wv[5], hv[8];
    #pragma unroll
    for (int g = 0; g < 5; ++g) wv[g] = wp[(size_t)k4 * 1280 + g];
    #pragma unroll
    for (int i = 0; i < 8; ++i)
      hv[i] = *(const float4*)&hb[i * 256 + k4 * 4];
    #pragma unroll
    for (int i = 0; i < 8; ++i)
      #pragma unroll
      for (int g = 0; g < 5; ++g) {
        acc[i][g] = fmaf(hv[i].x, wv[g].x, acc[i][g]);
        acc[i][g] = fmaf(hv[i].y, wv[g].y, acc[i][g]);
        acc[i][g] = fmaf(hv[i].z, wv[g].z, acc[i][g]);
        acc[i][g] = fmaf(hv[i].w, wv[g].w, acc[i][g]);
      }
  }
  for (int i = 0; i < 8; ++i) {
    int r = rt * 64 + rg * 8 + i;
    for (int g = 0; g < 5; ++g) {
      int j = g * 256 + jh;
      xw[(size_t)r * 1280 + j] = acc[i][g] + bih[j] + bhh[j];
    }
  }
}

// ---------------- per-step kernel (R10 champion geometry) ----------------
// grid = 256 blocks (rt 32 x cg 8), 256 threads, R=4 rows/thread.
// Phase C resamples step t-1, phase A computes step t.
__global__ __launch_bounds__(256, 2) void step_kernel(
    int t, unsigned ke0, unsigned ke1, unsigned kr0, unsigned kr1,
    const float* __restrict__ h_prev, const float* __restrict__ c_prev,
    float* __restrict__ h_next, float* __restrict__ c_next,
    const float* __restrict__ parts_prev, float* __restrict__ parts_cur,
    const float* __restrict__ labparts_prev, float* __restrict__ labparts_cur,
    const float* __restrict__ ps_prev, float* __restrict__ ps_out,
    float* __restrict__ lab_out, float* __restrict__ pf_out,
    const float* __restrict__ xdot, const float* __restrict__ xw,
    const float4* __restrict__ Wt5hh, const float* __restrict__ Wf,
    const float* __restrict__ Wlab, const float* __restrict__ blab) {
  const int tid = threadIdx.x;
  const int cg = blockIdx.x & 7;
  const int rt = blockIdx.x >> 3;

  __shared__ float sarr[1024];
  __shared__ float mtab[32], ltab[32];
  __shared__ int   flat_s[32];
  __shared__ float h_s[32 * 256];

  if (t == 0) {
    if (tid < 32) flat_s[tid] = rt * 32 + tid;   // identity gather
  } else {
    // ---- phase C: resample step t-1 ----
    for (int idx = tid; idx < 1024; idx += 256) {
      float lp = 0.0f;
      #pragma unroll
      for (int c2 = 0; c2 < 8; ++c2) lp += parts_prev[c2 * 1024 + idx];
      lp += xdot[(t - 1) * 32 + (idx & 31)];
      float pp = ps_prev ? ps_prev[idx] : -3.4657359f;  // log(1/32)
      sarr[idx] = lp + pp;
    }
    __syncthreads();
    if (tid < 32) {  // per-b softmax stats over particles
      const int b = tid;
      float m = -INFINITY;
      for (int k = 0; k < 32; ++k) m = fmaxf(m, sarr[k * 32 + b]);
      float s = 0.0f;
      for (int k = 0; k < 32; ++k) s += expf(sarr[k * 32 + b] - m);
      mtab[b] = m; ltab[b] = logf(s);
    }
    __syncthreads();
    {
      // Gumbel argmax for (k=rt, b=q) rows: 8 lanes per row, 4 j each
      const int q = tid >> 3, s8 = tid & 7;
      const float m = mtab[q], l = ltab[q];
      float best = -INFINITY; int bestj = 0;
      for (int jj = 0; jj < 4; ++jj) {
        int j = s8 * 4 + jj;
        unsigned bits = tfx(kr0, kr1, (unsigned)(rt * 1024 + q * 32 + j));
        float u01 = __uint_as_float(0x3f800000u | (bits >> 9)) - 1.0f;
        float u = fmaxf(u01, 1.17549435e-38f);
        float g = -logf(-logf(u));
        float p1 = sarr[j * 32 + q] - m - l;
        float z = g + logf(fmaf(0.5f, expf(p1), 0.015625f));
        if (z > best) { best = z; bestj = j; }
      }
      #pragma unroll
      for (int mm = 1; mm < 8; mm <<= 1) {
        float ob = __shfl_xor(best, mm);
        int   oj = __shfl_xor(bestj, mm);
        if (ob > best || (ob == best && oj < bestj)) { best = ob; bestj = oj; }
      }
      if (s8 == 0) {
        int fl = bestj * 32 + q;
        flat_s[q] = fl;
        if (cg == 0) {   // unnormalized importance-corrected log-weight
          float p1f = sarr[fl] - m - l;
          float e = expf(p1f);
          ps_out[rt * 32 + q] = logf(e / fmaf(0.5f, e, 0.015625f));
        }
      }
    }
    if (cg == 0) {  // gathered label-head dot for outputs of step t-1
      __syncthreads();
      if (tid < 32) {
        int fl = flat_s[tid];
        float lab = 0.0f;
        #pragma unroll
        for (int c2 = 0; c2 < 8; ++c2) lab += labparts_prev[c2 * 1024 + fl];
        lab_out[rt * 32 + tid] = lab;
        float v = lab + blab[0];
        pf_out[rt * 32 + tid] = 1.0f / (1.0f + expf(-v));
      }
    }
  }
  __syncthreads();

  // ---- phase A: stage gathered h rows into LDS ----
  {
    float4* dst = (float4*)h_s;
    for (int i = tid; i < 32 * 64; i += 256) {
      int rr = i >> 6, kc = i & 63;
      dst[i] = *(const float4*)(h_prev + (size_t)flat_s[rr] * 256 + kc * 4);
    }
  }
  __syncthreads();

  const int rg = tid >> 5, hcol = tid & 31;  // rg in [0,8): 4 rows each
  const int jh = cg * 32 + hcol;             // hidden index 0..255
  const float4* wp = Wt5hh + (size_t)jh * 5;
  const float* hb = h_s + rg * 4 * 256;
  float acc[4][5] = {};
  #pragma unroll 4
  for (int k4 = 0; k4 < 64; ++k4) {
    float4 wv[5], hv[4];
    #pragma unroll
    for (int g = 0; g < 5; ++g) wv[g] = wp[(size_t)k4 * 1280 + g];
    #pragma unroll
    for (int i = 0; i < 4; ++i)
      hv[i] = *(const float4*)&hb[i * 256 + k4 * 4];
    #pragma unroll
    for (int i = 0; i < 4; ++i)
      #pragma unroll
      for (int g = 0; g < 5; ++g) {
        acc[i][g] = fmaf(hv[i].x, wv[g].x, acc[i][g]);
        acc[i][g] = fmaf(hv[i].y, wv[g].y, acc[i][g]);
        acc[i][g] = fmaf(hv[i].z, wv[g].z, acc[i][g]);
        acc[i][g] = fmaf(hv[i].w, wv[g].w, acc[i][g]);
      }
  }

  const float wfj = Wf[jh];
  const float wlj = Wlab[jh];
  #pragma unroll
  for (int i = 0; i < 4; ++i) {
    const int rl = rg * 4 + i;             // local row == b
    const int kb = rt * 32 + rl;
    const float* xr = xw + (size_t)(t * 32 + rl) * 1280;
    float gi = acc[i][0] + xr[jh];
    float gf = acc[i][1] + xr[256 + jh];
    float gg = acc[i][2] + xr[512 + jh];
    float go = acc[i][3] + xr[768 + jh];
    float gv = acc[i][4] + xr[1024 + jh];
    float cp = c_prev[(size_t)flat_s[rl] * 256 + jh];
    float c1 = sigf(gf) * cp + sigf(gi) * tanhf(gg);
    unsigned bits = tfx(ke0, ke1, (unsigned)(kb * 256 + jh));
    float z = normal_from_bits(bits);
    float sp = fmaxf(gv, 0.0f) + log1pf(expf(-fabsf(gv)));  // softplus
    c1 = c1 + z * sp;
    float h1 = sigf(go) * tanhf(c1);
    h_next[(size_t)kb * 256 + jh] = h1;
    c_next[(size_t)kb * 256 + jh] = c1;
    float ph = h1 * wfj, pb = h1 * wlj;
    #pragma unroll
    for (int mm = 1; mm < 32; mm <<= 1) {
      ph += __shfl_xor(ph, mm);
      pb += __shfl_xor(pb, mm);
    }
    if (hcol == 0) {
      parts_cur[cg * 1024 + kb] = ph;
      labparts_cur[cg * 1024 + kb] = pb;
    }
  }
}

// ---------------- tail resample (t=63): one block per particle -------------
__global__ __launch_bounds__(256, 2) void tail_resample_kernel(
    unsigned kr0, unsigned kr1,
    const float* __restrict__ parts_prev,
    const float* __restrict__ labparts_prev,
    const float* __restrict__ ps_prev, float* __restrict__ ps_out,
    float* __restrict__ lab_out, float* __restrict__ pf_out,
    const float* __restrict__ xdot, const float* __restrict__ blab) {
  const int tid = threadIdx.x;
  const int rt = blockIdx.x;      // particle

  __shared__ float sarr[1024];
  __shared__ float mtab[32], ltab[32];
  __shared__ int   flat_s[32];

  for (int idx = tid; idx < 1024; idx += 256) {
    float lp = 0.0f;
    #pragma unroll
    for (int c2 = 0; c2 < 8; ++c2) lp += parts_prev[c2 * 1024 + idx];
    lp += xdot[63 * 32 + (idx & 31)];
    float pp = ps_prev[idx];
    sarr[idx] = lp + pp;
  }
  __syncthreads();
  if (tid < 32) {
    const int b = tid;
    float m = -INFINITY;
    for (int k = 0; k < 32; ++k) m = fmaxf(m, sarr[k * 32 + b]);
    float s = 0.0f;
    for (int k = 0; k < 32; ++k) s += expf(sarr[k * 32 + b] - m);
    mtab[b] = m; ltab[b] = logf(s);
  }
  __syncthreads();
  {
    const int q = tid >> 3, s8 = tid & 7;
    const float m = mtab[q], l = ltab[q];
    float best = -INFINITY; int bestj = 0;
    for (int jj = 0; jj < 4; ++jj) {
      int j = s8 * 4 + jj;
      unsigned bits = tfx(kr0, kr1, (unsigned)(rt * 1024 + q * 32 + j));
      float u01 = __uint_as_float(0x3f800000u | (bits >> 9)) - 1.0f;
      float u = fmaxf(u01, 1.17549435e-38f);
      float g = -logf(-logf(u));
      float p1 = sarr[j * 32 + q] - m - l;
      float z = g + logf(fmaf(0.5f, expf(p1), 0.015625f));
      if (z > best) { best = z; bestj = j; }
    }
    #pragma unroll
    for (int mm = 1; mm < 8; mm <<= 1) {
      float ob = __shfl_xor(best, mm);
      int   oj = __shfl_xor(bestj, mm);
      if (ob > best || (ob == best && oj < bestj)) { best = ob; bestj = oj; }
    }
    if (s8 == 0) {
      int fl = bestj * 32 + q;
      flat_s[q] = fl;
      float p1f = sarr[fl] - m - l;
      float e = expf(p1f);
      ps_out[rt * 32 + q] = logf(e / fmaf(0.5f, e, 0.015625f));
    }
  }
  __syncthreads();
  if (tid < 32) {
    int fl = flat_s[tid];
    float lab = 0.0f;
    #pragma unroll
    for (int c2 = 0; c2 < 8; ++c2) lab += labparts_prev[c2 * 1024 + fl];
    lab_out[rt * 32 + tid] = lab;
    float v = lab + blab[0];
    pf_out[rt * 32 + tid] = 1.0f / (1.0f + expf(-v));
  }
}

// ---------------- final: weighted particle mean -> y_out ----------------
__global__ __launch_bounds__(256) void final_kernel(
    const float* __restrict__ ps_store, const float* __restrict__ lab_full,
    const float* __restrict__ blab, float* __restrict__ yout) {
  int idx = blockIdx.x * 256 + threadIdx.x;  // T*B = 2048
  if (idx >= 2048) return;
  int t = idx >> 5, b = idx & 31;
  const float* pl = ps_store + (size_t)t * 1024 + b;
  const float* lb = lab_full + (size_t)t * 1024 + b;
  float m = -INFINITY;
  for (int k = 0; k < 32; ++k) m = fmaxf(m, pl[k * 32]);
  float num = 0.0f, den = 0.0f;
  for (int k = 0; k < 32; ++k) {
    float w = expf(pl[k * 32] - m);
    num += w * lb[k * 32];
    den += w;
  }
  float y = num / den;
  yout[idx] = 1.0f / (1.0f + expf(-(y + blab[0])));
}

// ---------------- host ----------------
extern "C" void kernel_launch(void* const* d_in, const int* in_sizes, int n_in,
                              void* d_out, int out_size, void* d_ws,
                              size_t ws_size, hipStream_t stream) {
  const float* obs  = (const float*)d_in[0];
  const float* win  = (const float*)d_in[1];
  const float* Wobs = (const float*)d_in[2];
  const float* bobs = (const float*)d_in[3];
  const float* Wact = (const float*)d_in[4];
  const float* bact = (const float*)d_in[5];
  const float* Wih  = (const float*)d_in[6];
  const float* bih  = (const float*)d_in[7];
  const float* Whh  = (const float*)d_in[8];
  const float* bhh  = (const float*)d_in[9];
  const float* Wf   = (const float*)d_in[10];
  const float* bf   = (const float*)d_in[11];
  const float* Wlab = (const float*)d_in[12];
  const float* blab = (const float*)d_in[13];
  const float* h0   = (const float*)d_in[14];
  const float* c0   = (const float*)d_in[15];
  float* out = (float*)d_out;

  char* ws = (char*)d_ws;
  float* embT = (float*)ws;                 ws += (size_t)2048 * 256 * 4;
  float* xw   = (float*)ws;                 ws += (size_t)2048 * 1280 * 4;
  float* xd   = (float*)ws;                 ws += (size_t)2048 * 4;
  float* hbuf[2]; float* cbuf[2];
  hbuf[0] = (float*)ws;                     ws += (size_t)1024 * 256 * 4;
  hbuf[1] = (float*)ws;                     ws += (size_t)1024 * 256 * 4;
  cbuf[0] = (float*)ws;                     ws += (size_t)1024 * 256 * 4;
  cbuf[1] = (float*)ws;                     ws += (size_t)1024 * 256 * 4;
  float* parts    = (float*)ws;             ws += (size_t)2 * 8 * 1024 * 4;
  float* labparts = (float*)ws;             ws += (size_t)2 * 8 * 1024 * 4;
  float* psst     = (float*)ws;             ws += (size_t)64 * 1024 * 4;
  float* labf     = (float*)ws;             ws += (size_t)64 * 1024 * 4;

  // Aliased transposed-weight buffers (no net workspace growth):
  // Wt5ih: starts at hbuf[1], 1.31 MB (spills 0.26 MB into cbuf[0]) — last
  //        read by xw_kernel, which completes before step 0 writes hbuf/cbuf
  //        (stream-serial; step 0 reads c from the pristine c0 input).
  // Wt5hh: embT region (2 MB) — embT dead after xw_kernel/xdot_kernel.
  float4* Wt5ih = (float4*)hbuf[1];
  float4* Wt5hh = (float4*)embT;

  transpose_w_kernel<<<320, 256, 0, stream>>>(Wih, Wt5ih);
  emb_kernel<<<2048, 256, 0, stream>>>(obs, win, Wobs, bobs, Wact, bact, embT);
  xw_kernel<<<256, 256, 0, stream>>>(embT, Wt5ih, bih, bhh, xw);
  xdot_kernel<<<512, 256, 0, stream>>>(embT, Wf, bf, xd);
  transpose_w_kernel<<<320, 256, 0, stream>>>(Whh, Wt5hh);

  for (int t = 0; t < 64; ++t) {
    unsigned a0, a1, ke0 = 0, ke1 = 0, kr0 = 0, kr1 = 0;
    tf2x32(0u, 42u, 0u, (unsigned)t, a0, a1);
    tf2x32(a0, a1, 0u, 0u, ke0, ke1);
    if (t >= 1) {  // k_res of step t-1 (resample performed this launch)
      tf2x32(0u, 42u, 0u, (unsigned)(t - 1), a0, a1);
      tf2x32(a0, a1, 0u, 1u, kr0, kr1);
    }
    const float* hp = (t == 0) ? h0 : hbuf[(t - 1) & 1];
    const float* cp = (t == 0) ? c0 : cbuf[(t - 1) & 1];
    float* hn = hbuf[t & 1];
    float* cn = cbuf[t & 1];
    const float* pprev = (t >= 2) ? psst + (size_t)(t - 2) * 1024 : nullptr;
    int tm1 = (t >= 1) ? (t - 1) : 0;
    step_kernel<<<256, 256, 0, stream>>>(
        t, ke0, ke1, kr0, kr1, hp, cp, hn, cn,
        parts + (size_t)((t + 1) & 1) * 8192, parts + (size_t)(t & 1) * 8192,
        labparts + (size_t)((t + 1) & 1) * 8192,
        labparts + (size_t)(t & 1) * 8192,
        pprev, psst + (size_t)tm1 * 1024, labf + (size_t)tm1 * 1024,
        out + 2048 + (size_t)tm1 * 1024,
        xd, xw, Wt5hh, Wf, Wlab, blab);
  }

  {  // resample for t=63 (32 blocks)
    unsigned a0, a1, kr0, kr1;
    tf2x32(0u, 42u, 0u, 63u, a0, a1);
    tf2x32(a0, a1, 0u, 1u, kr0, kr1);
    tail_resample_kernel<<<32, 256, 0, stream>>>(
        kr0, kr1, parts + 8192, labparts + 8192,
        psst + (size_t)62 * 1024, psst + (size_t)63 * 1024,
        labf + (size_t)63 * 1024, out + 2048 + (size_t)63 * 1024, xd, blab);
  }

  final_kernel<<<8, 256, 0, stream>>>(psst, labf, blab, out);
  (void)in_sizes; (void)n_in; (void)out_size; (void)ws_size;
}